// Round 4
// baseline (693.095 us; speedup 1.0000x reference)
//
#include <hip/hip_runtime.h>
#include <cstdint>
#include <cstddef>

#define N_NODES_C 100000
#define N_EDGES_C 1600000
#define LN_EPS_C 1e-5f
#define CLAMP_C 1.8f

__device__ __forceinline__ float readlane_f(float v, int l) {
  return __uint_as_float(__builtin_amdgcn_readlane(__float_as_uint(v), l));
}

__device__ __forceinline__ float wave_sum(float v) {
#pragma unroll
  for (int off = 32; off > 0; off >>= 1) v += __shfl_xor(v, off, 64);
  return v;
}

// ---------------- CSR build ----------------
__global__ void hist_kernel(const int* __restrict__ row, int* __restrict__ counts) {
  int stride = gridDim.x * blockDim.x;
  for (int e = blockIdx.x * blockDim.x + threadIdx.x; e < N_EDGES_C; e += stride)
    atomicAdd(&counts[row[e]], 1);
}

__global__ void scan1_kernel(const int* __restrict__ counts, int* __restrict__ rowstart,
                             int* __restrict__ bsums) {
  __shared__ int lds[256];
  int t = threadIdx.x;
  int base = blockIdx.x * 1024 + t * 4;
  int c0 = (base + 0 < N_NODES_C) ? counts[base + 0] : 0;
  int c1 = (base + 1 < N_NODES_C) ? counts[base + 1] : 0;
  int c2 = (base + 2 < N_NODES_C) ? counts[base + 2] : 0;
  int c3 = (base + 3 < N_NODES_C) ? counts[base + 3] : 0;
  int s = c0 + c1 + c2 + c3;
  lds[t] = s;
  __syncthreads();
#pragma unroll
  for (int off = 1; off < 256; off <<= 1) {
    int v = (t >= off) ? lds[t - off] : 0;
    __syncthreads();
    lds[t] += v;
    __syncthreads();
  }
  int incl = lds[t];
  int excl = incl - s;
  if (t == 255) bsums[blockIdx.x] = incl;
  if (base + 0 < N_NODES_C) rowstart[base + 0] = excl;
  excl += c0;
  if (base + 1 < N_NODES_C) rowstart[base + 1] = excl;
  excl += c1;
  if (base + 2 < N_NODES_C) rowstart[base + 2] = excl;
  excl += c2;
  if (base + 3 < N_NODES_C) rowstart[base + 3] = excl;
}

__global__ void scan2_kernel(int* __restrict__ bsums, int nb) {
  __shared__ int lds[128];
  int t = threadIdx.x;
  int v = (t < nb) ? bsums[t] : 0;
  lds[t] = v;
  __syncthreads();
#pragma unroll
  for (int off = 1; off < 128; off <<= 1) {
    int u = (t >= off) ? lds[t - off] : 0;
    __syncthreads();
    lds[t] += u;
    __syncthreads();
  }
  if (t < nb) bsums[t] = lds[t] - v;
}

// writes final rowstart AND an identical cursor copy for the scatter pass
__global__ void scan3_kernel(int* __restrict__ rowstart, int* __restrict__ cursor,
                             const int* __restrict__ bsums) {
  int add = bsums[blockIdx.x];
  int base = blockIdx.x * 1024 + threadIdx.x * 4;
#pragma unroll
  for (int i = 0; i < 4; ++i)
    if (base + i < N_NODES_C) {
      int v = rowstart[base + i] + add;
      rowstart[base + i] = v;
      cursor[base + i] = v;
    }
}

// packed (col, val) scatter: ONE 8B store per edge instead of two 4B stores
__global__ void scatter_kernel(const int* __restrict__ row, const int* __restrict__ col,
                               const float* __restrict__ vals, int* __restrict__ cursor,
                               int2* __restrict__ edges_s) {
  int stride = gridDim.x * blockDim.x;
  for (int e = blockIdx.x * blockDim.x + threadIdx.x; e < N_EDGES_C; e += stride) {
    int r = row[e];
    int p = atomicAdd(&cursor[r], 1);
    edges_s[p] = make_int2(col[e], __float_as_int(vals[e]));
  }
}

// ---------------- clamp + LayerNorm + GEMM1 (100 -> 64) ----------------
__global__ __launch_bounds__(256) void ln_gemm1_kernel(
    const float* __restrict__ x, const float* __restrict__ gamma, const float* __restrict__ beta,
    const float* __restrict__ W1, const float* __restrict__ b1, float* __restrict__ y) {
  int lane = threadIdx.x & 63;
  int wid = blockIdx.x * (blockDim.x >> 6) + (threadIdx.x >> 6);
  int nw = gridDim.x * (blockDim.x >> 6);
  float w[100];
#pragma unroll
  for (int k = 0; k < 100; ++k) w[k] = W1[k * 64 + lane];
  float bias = b1[lane];
  float g0 = gamma[lane];
  float be0 = beta[lane];
  float g1 = (lane < 36) ? gamma[64 + lane] : 0.f;
  float be1 = (lane < 36) ? beta[64 + lane] : 0.f;
  for (int n = wid; n < N_NODES_C; n += nw) {
    const float* xr = x + (size_t)n * 100;
    float x0 = xr[lane];
    float x1 = (lane < 36) ? xr[64 + lane] : 0.f;
    x0 = fminf(fmaxf(x0, -CLAMP_C), CLAMP_C);
    x1 = fminf(fmaxf(x1, -CLAMP_C), CLAMP_C);
    float mu = wave_sum(x0 + x1) * 0.01f;
    float d0 = x0 - mu;
    float d1 = (lane < 36) ? (x1 - mu) : 0.f;
    float var = wave_sum(d0 * d0 + d1 * d1) * 0.01f;
    float inv = rsqrtf(var + LN_EPS_C);
    float xn0 = d0 * inv * g0 + be0;
    float xn1 = d1 * inv * g1 + be1;
    float acc = bias;
#pragma unroll
    for (int k = 0; k < 64; ++k) acc = fmaf(readlane_f(xn0, k), w[k], acc);
#pragma unroll
    for (int k = 0; k < 36; ++k) acc = fmaf(readlane_f(xn1, k), w[64 + k], acc);
    y[(size_t)n * 64 + lane] = acc;
  }
}

// ---------------- fused SpMM(D=64) -> ELU -> GEMM(64->DOUT) ----------------
// gather pitch 64; output pitch OPITCH (64 or 48)
template <int DOUT, int OPITCH>
__global__ __launch_bounds__(256) void spmm_elu_gemm_kernel(
    const int* __restrict__ rowstart, const int* __restrict__ counts,
    const int2* __restrict__ edges_s, const float* __restrict__ y,
    const float* __restrict__ W, const float* __restrict__ b, float* __restrict__ out) {
  int lane = threadIdx.x & 63;
  int wid = blockIdx.x * (blockDim.x >> 6) + (threadIdx.x >> 6);
  int nw = gridDim.x * (blockDim.x >> 6);
  float w[64];
#pragma unroll
  for (int k = 0; k < 64; ++k) w[k] = (lane < DOUT) ? W[k * DOUT + lane] : 0.f;
  float bias = (lane < DOUT) ? b[lane] : 0.f;
  for (int n = wid; n < N_NODES_C; n += nw) {
    int start = rowstart[n];
    int cnt = counts[n];
    float acc = 0.f;
    for (int base = 0; base < cnt; base += 64) {
      int m = cnt - base;
      if (m > 64) m = 64;
      int2 ev = make_int2(0, 0);
      if (lane < m) ev = edges_s[start + base + lane];
      for (int j = 0; j < m; ++j) {
        int c = __builtin_amdgcn_readlane(ev.x, j);
        float v = __uint_as_float(__builtin_amdgcn_readlane((unsigned)ev.y, j));
        acc = fmaf(v, y[(size_t)c * 64 + lane], acc);
      }
    }
    // ELU
    float xe = (acc > 0.f) ? acc : expm1f(acc);
    // GEMM: out[n][lane] = bias + sum_k xe_k * W[k][lane]
    float o = bias;
#pragma unroll
    for (int k = 0; k < 64; ++k) o = fmaf(readlane_f(xe, k), w[k], o);
    if (lane < DOUT) out[(size_t)n * OPITCH + lane] = o;
  }
}

// ---------------- final SpMM (gather pitch 48, D=47) -> d_out ----------------
__global__ __launch_bounds__(256) void spmm_final_kernel(
    const int* __restrict__ rowstart, const int* __restrict__ counts,
    const int2* __restrict__ edges_s, const float* __restrict__ y,
    float* __restrict__ out) {
  int lane = threadIdx.x & 63;
  int wid = blockIdx.x * (blockDim.x >> 6) + (threadIdx.x >> 6);
  int nw = gridDim.x * (blockDim.x >> 6);
  for (int n = wid; n < N_NODES_C; n += nw) {
    int start = rowstart[n];
    int cnt = counts[n];
    float acc = 0.f;
    for (int base = 0; base < cnt; base += 64) {
      int m = cnt - base;
      if (m > 64) m = 64;
      int2 ev = make_int2(0, 0);
      if (lane < m) ev = edges_s[start + base + lane];
      for (int j = 0; j < m; ++j) {
        int c = __builtin_amdgcn_readlane(ev.x, j);
        float v = __uint_as_float(__builtin_amdgcn_readlane((unsigned)ev.y, j));
        float yv = (lane < 47) ? y[(size_t)c * 48 + lane] : 0.f;
        acc = fmaf(v, yv, acc);
      }
    }
    if (lane < 47) out[(size_t)n * 47 + lane] = acc;
  }
}

extern "C" void kernel_launch(void* const* d_in, const int* in_sizes, int n_in,
                              void* d_out, int out_size, void* d_ws, size_t ws_size,
                              hipStream_t stream) {
  const float* x = (const float*)d_in[0];
  const float* adj_vals = (const float*)d_in[1];
  const int* adj_row = (const int*)d_in[2];
  const int* adj_col = (const int*)d_in[3];
  const float* gamma = (const float*)d_in[4];
  const float* beta = (const float*)d_in[5];
  const float* W1 = (const float*)d_in[6];
  const float* b1 = (const float*)d_in[7];
  const float* W2 = (const float*)d_in[8];
  const float* b2 = (const float*)d_in[9];
  const float* W3 = (const float*)d_in[10];
  const float* b3 = (const float*)d_in[11];
  float* out = (float*)d_out;

  char* ws = (char*)d_ws;
  size_t off = 0;
  auto alloc = [&](size_t bytes) -> void* {
    void* p = ws + off;
    off += (bytes + 255) & ~(size_t)255;
    return p;
  };
  float* bufA = (float*)alloc(sizeof(float) * (size_t)N_NODES_C * 64);
  float* bufB = (float*)alloc(sizeof(float) * (size_t)N_NODES_C * 64);
  int* counts = (int*)alloc(sizeof(int) * N_NODES_C);
  int* cursor = (int*)alloc(sizeof(int) * N_NODES_C);
  int* rowstart = (int*)alloc(sizeof(int) * N_NODES_C);
  int* bsums = (int*)alloc(sizeof(int) * 256);
  int2* edges_s = (int2*)alloc(sizeof(int2) * N_EDGES_C);

  hipMemsetAsync(counts, 0, sizeof(int) * N_NODES_C, stream);

  hist_kernel<<<2048, 256, 0, stream>>>(adj_row, counts);
  int nb = (N_NODES_C + 1023) / 1024;  // 98
  scan1_kernel<<<nb, 256, 0, stream>>>(counts, rowstart, bsums);
  scan2_kernel<<<1, 128, 0, stream>>>(bsums, nb);
  scan3_kernel<<<nb, 256, 0, stream>>>(rowstart, cursor, bsums);
  scatter_kernel<<<2048, 256, 0, stream>>>(adj_row, adj_col, adj_vals, cursor, edges_s);

  // h1 = LN(clamp(x)) @ W1 + b1
  ln_gemm1_kernel<<<1024, 256, 0, stream>>>(x, gamma, beta, W1, b1, bufA);
  // h2 = ELU(spmm(h1)) @ W2 + b2   (pitch 64)
  spmm_elu_gemm_kernel<64, 64><<<2048, 256, 0, stream>>>(rowstart, counts, edges_s, bufA,
                                                         W2, b2, bufB);
  // h3 = ELU(spmm(h2)) @ W3 + b3   (pitch 48, 47 valid)
  spmm_elu_gemm_kernel<47, 48><<<2048, 256, 0, stream>>>(rowstart, counts, edges_s, bufB,
                                                         W3, b3, bufA);
  // out = spmm(h3)
  spmm_final_kernel<<<2048, 256, 0, stream>>>(rowstart, counts, edges_s, bufA, out);
}

// Round 5
// 490.010 us; speedup vs baseline: 1.4145x; 1.4145x over previous
//
#include <hip/hip_runtime.h>
#include <cstdint>
#include <cstddef>

#define N_NODES_C 100000
#define N_EDGES_C 1600000
#define LN_EPS_C 1e-5f
#define CLAMP_C 1.8f

__device__ __forceinline__ float readlane_f(float v, int l) {
  return __uint_as_float(__builtin_amdgcn_readlane(__float_as_uint(v), l));
}

__device__ __forceinline__ float wave_sum(float v) {
#pragma unroll
  for (int off = 32; off > 0; off >>= 1) v += __shfl_xor(v, off, 64);
  return v;
}

// ---------------- CSR build ----------------
__global__ void hist_kernel(const int* __restrict__ row, int* __restrict__ counts) {
  int stride = gridDim.x * blockDim.x;
  for (int e = blockIdx.x * blockDim.x + threadIdx.x; e < N_EDGES_C; e += stride)
    atomicAdd(&counts[row[e]], 1);
}

__global__ void scan1_kernel(const int* __restrict__ counts, int* __restrict__ rowstart,
                             int* __restrict__ bsums) {
  __shared__ int lds[256];
  int t = threadIdx.x;
  int base = blockIdx.x * 1024 + t * 4;
  int c0 = (base + 0 < N_NODES_C) ? counts[base + 0] : 0;
  int c1 = (base + 1 < N_NODES_C) ? counts[base + 1] : 0;
  int c2 = (base + 2 < N_NODES_C) ? counts[base + 2] : 0;
  int c3 = (base + 3 < N_NODES_C) ? counts[base + 3] : 0;
  int s = c0 + c1 + c2 + c3;
  lds[t] = s;
  __syncthreads();
#pragma unroll
  for (int off = 1; off < 256; off <<= 1) {
    int v = (t >= off) ? lds[t - off] : 0;
    __syncthreads();
    lds[t] += v;
    __syncthreads();
  }
  int incl = lds[t];
  int excl = incl - s;
  if (t == 255) bsums[blockIdx.x] = incl;
  if (base + 0 < N_NODES_C) rowstart[base + 0] = excl;
  excl += c0;
  if (base + 1 < N_NODES_C) rowstart[base + 1] = excl;
  excl += c1;
  if (base + 2 < N_NODES_C) rowstart[base + 2] = excl;
  excl += c2;
  if (base + 3 < N_NODES_C) rowstart[base + 3] = excl;
}

__global__ void scan2_kernel(int* __restrict__ bsums, int nb) {
  __shared__ int lds[128];
  int t = threadIdx.x;
  int v = (t < nb) ? bsums[t] : 0;
  lds[t] = v;
  __syncthreads();
#pragma unroll
  for (int off = 1; off < 128; off <<= 1) {
    int u = (t >= off) ? lds[t - off] : 0;
    __syncthreads();
    lds[t] += u;
    __syncthreads();
  }
  if (t < nb) bsums[t] = lds[t] - v;
}

// writes final rowstart AND an identical cursor copy for the scatter pass
__global__ void scan3_kernel(int* __restrict__ rowstart, int* __restrict__ cursor,
                             const int* __restrict__ bsums) {
  int add = bsums[blockIdx.x];
  int base = blockIdx.x * 1024 + threadIdx.x * 4;
#pragma unroll
  for (int i = 0; i < 4; ++i)
    if (base + i < N_NODES_C) {
      int v = rowstart[base + i] + add;
      rowstart[base + i] = v;
      cursor[base + i] = v;
    }
}

// packed (col, val) scatter: ONE 8B store per edge
__global__ void scatter_kernel(const int* __restrict__ row, const int* __restrict__ col,
                               const float* __restrict__ vals, int* __restrict__ cursor,
                               int2* __restrict__ edges_s) {
  int stride = gridDim.x * blockDim.x;
  for (int e = blockIdx.x * blockDim.x + threadIdx.x; e < N_EDGES_C; e += stride) {
    int r = row[e];
    int p = atomicAdd(&cursor[r], 1);
    edges_s[p] = make_int2(col[e], __float_as_int(vals[e]));
  }
}

// ---------------- clamp + LayerNorm + GEMM1 (100 -> 64) ----------------
__global__ __launch_bounds__(256) void ln_gemm1_kernel(
    const float* __restrict__ x, const float* __restrict__ gamma, const float* __restrict__ beta,
    const float* __restrict__ W1, const float* __restrict__ b1, float* __restrict__ y) {
  int lane = threadIdx.x & 63;
  int wid = blockIdx.x * (blockDim.x >> 6) + (threadIdx.x >> 6);
  int nw = gridDim.x * (blockDim.x >> 6);
  float w[100];
#pragma unroll
  for (int k = 0; k < 100; ++k) w[k] = W1[k * 64 + lane];
  float bias = b1[lane];
  float g0 = gamma[lane];
  float be0 = beta[lane];
  float g1 = (lane < 36) ? gamma[64 + lane] : 0.f;
  float be1 = (lane < 36) ? beta[64 + lane] : 0.f;
  for (int n = wid; n < N_NODES_C; n += nw) {
    const float* xr = x + (size_t)n * 100;
    float x0 = xr[lane];
    float x1 = (lane < 36) ? xr[64 + lane] : 0.f;
    x0 = fminf(fmaxf(x0, -CLAMP_C), CLAMP_C);
    x1 = fminf(fmaxf(x1, -CLAMP_C), CLAMP_C);
    float mu = wave_sum(x0 + x1) * 0.01f;
    float d0 = x0 - mu;
    float d1 = (lane < 36) ? (x1 - mu) : 0.f;
    float var = wave_sum(d0 * d0 + d1 * d1) * 0.01f;
    float inv = rsqrtf(var + LN_EPS_C);
    float xn0 = d0 * inv * g0 + be0;
    float xn1 = d1 * inv * g1 + be1;
    float acc = bias;
#pragma unroll
    for (int k = 0; k < 64; ++k) acc = fmaf(readlane_f(xn0, k), w[k], acc);
#pragma unroll
    for (int k = 0; k < 36; ++k) acc = fmaf(readlane_f(xn1, k), w[64 + k], acc);
    y[(size_t)n * 64 + lane] = acc;
  }
}

// ---------------- SpMM core with 8-way gather ILP ----------------
// Gather pitch 64 (input always 64 valid lanes in fused mode).
// Masked edge load zero-pads lanes >= m, so iterating j up to round-up-8 is
// safe: pad entries have val=0 and gather y[row 0] (L1-hot, contributes 0).
template <int DOUT, int OPITCH>
__global__ __launch_bounds__(256) void spmm_elu_gemm_kernel(
    const int* __restrict__ rowstart, const int* __restrict__ counts,
    const int2* __restrict__ edges_s, const float* __restrict__ y,
    const float* __restrict__ W, const float* __restrict__ b, float* __restrict__ out) {
  int lane = threadIdx.x & 63;
  int wid = blockIdx.x * (blockDim.x >> 6) + (threadIdx.x >> 6);
  int nw = gridDim.x * (blockDim.x >> 6);
  float w[64];
#pragma unroll
  for (int k = 0; k < 64; ++k) w[k] = (lane < DOUT) ? W[k * DOUT + lane] : 0.f;
  float bias = (lane < DOUT) ? b[lane] : 0.f;
  for (int n = wid; n < N_NODES_C; n += nw) {
    int start = rowstart[n];
    int cnt = counts[n];
    float a0 = 0.f, a1 = 0.f, a2 = 0.f, a3 = 0.f, a4 = 0.f, a5 = 0.f, a6 = 0.f, a7 = 0.f;
    for (int base = 0; base < cnt; base += 64) {
      int m = cnt - base;
      if (m > 64) m = 64;
      int2 ev = make_int2(0, 0);
      if (lane < m) ev = edges_s[start + base + lane];
      int mr = (m + 7) & ~7;
      for (int j = 0; j < mr; j += 8) {
        float g0 = y[(size_t)__builtin_amdgcn_readlane(ev.x, j + 0) * 64 + lane];
        float g1 = y[(size_t)__builtin_amdgcn_readlane(ev.x, j + 1) * 64 + lane];
        float g2 = y[(size_t)__builtin_amdgcn_readlane(ev.x, j + 2) * 64 + lane];
        float g3 = y[(size_t)__builtin_amdgcn_readlane(ev.x, j + 3) * 64 + lane];
        float g4 = y[(size_t)__builtin_amdgcn_readlane(ev.x, j + 4) * 64 + lane];
        float g5 = y[(size_t)__builtin_amdgcn_readlane(ev.x, j + 5) * 64 + lane];
        float g6 = y[(size_t)__builtin_amdgcn_readlane(ev.x, j + 6) * 64 + lane];
        float g7 = y[(size_t)__builtin_amdgcn_readlane(ev.x, j + 7) * 64 + lane];
        a0 = fmaf(__uint_as_float(__builtin_amdgcn_readlane((unsigned)ev.y, j + 0)), g0, a0);
        a1 = fmaf(__uint_as_float(__builtin_amdgcn_readlane((unsigned)ev.y, j + 1)), g1, a1);
        a2 = fmaf(__uint_as_float(__builtin_amdgcn_readlane((unsigned)ev.y, j + 2)), g2, a2);
        a3 = fmaf(__uint_as_float(__builtin_amdgcn_readlane((unsigned)ev.y, j + 3)), g3, a3);
        a4 = fmaf(__uint_as_float(__builtin_amdgcn_readlane((unsigned)ev.y, j + 4)), g4, a4);
        a5 = fmaf(__uint_as_float(__builtin_amdgcn_readlane((unsigned)ev.y, j + 5)), g5, a5);
        a6 = fmaf(__uint_as_float(__builtin_amdgcn_readlane((unsigned)ev.y, j + 6)), g6, a6);
        a7 = fmaf(__uint_as_float(__builtin_amdgcn_readlane((unsigned)ev.y, j + 7)), g7, a7);
      }
    }
    float acc = ((a0 + a1) + (a2 + a3)) + ((a4 + a5) + (a6 + a7));
    // ELU
    float xe = (acc > 0.f) ? acc : expm1f(acc);
    // GEMM: out[n][lane] = bias + sum_k xe_k * W[k][lane]
    float o = bias;
#pragma unroll
    for (int k = 0; k < 64; ++k) o = fmaf(readlane_f(xe, k), w[k], o);
    if (lane < DOUT) out[(size_t)n * OPITCH + lane] = o;
  }
}

// ---------------- final SpMM (gather pitch 48, 47 valid) -> d_out ----------------
__global__ __launch_bounds__(256) void spmm_final_kernel(
    const int* __restrict__ rowstart, const int* __restrict__ counts,
    const int2* __restrict__ edges_s, const float* __restrict__ y,
    float* __restrict__ out) {
  int lane = threadIdx.x & 63;
  int wid = blockIdx.x * (blockDim.x >> 6) + (threadIdx.x >> 6);
  int nw = gridDim.x * (blockDim.x >> 6);
  int lmask = (lane < 47) ? lane : 46;  // keep OOB lanes inside the row (values unused)
  for (int n = wid; n < N_NODES_C; n += nw) {
    int start = rowstart[n];
    int cnt = counts[n];
    float a0 = 0.f, a1 = 0.f, a2 = 0.f, a3 = 0.f, a4 = 0.f, a5 = 0.f, a6 = 0.f, a7 = 0.f;
    for (int base = 0; base < cnt; base += 64) {
      int m = cnt - base;
      if (m > 64) m = 64;
      int2 ev = make_int2(0, 0);
      if (lane < m) ev = edges_s[start + base + lane];
      int mr = (m + 7) & ~7;
      for (int j = 0; j < mr; j += 8) {
        float g0 = y[(size_t)__builtin_amdgcn_readlane(ev.x, j + 0) * 48 + lmask];
        float g1 = y[(size_t)__builtin_amdgcn_readlane(ev.x, j + 1) * 48 + lmask];
        float g2 = y[(size_t)__builtin_amdgcn_readlane(ev.x, j + 2) * 48 + lmask];
        float g3 = y[(size_t)__builtin_amdgcn_readlane(ev.x, j + 3) * 48 + lmask];
        float g4 = y[(size_t)__builtin_amdgcn_readlane(ev.x, j + 4) * 48 + lmask];
        float g5 = y[(size_t)__builtin_amdgcn_readlane(ev.x, j + 5) * 48 + lmask];
        float g6 = y[(size_t)__builtin_amdgcn_readlane(ev.x, j + 6) * 48 + lmask];
        float g7 = y[(size_t)__builtin_amdgcn_readlane(ev.x, j + 7) * 48 + lmask];
        a0 = fmaf(__uint_as_float(__builtin_amdgcn_readlane((unsigned)ev.y, j + 0)), g0, a0);
        a1 = fmaf(__uint_as_float(__builtin_amdgcn_readlane((unsigned)ev.y, j + 1)), g1, a1);
        a2 = fmaf(__uint_as_float(__builtin_amdgcn_readlane((unsigned)ev.y, j + 2)), g2, a2);
        a3 = fmaf(__uint_as_float(__builtin_amdgcn_readlane((unsigned)ev.y, j + 3)), g3, a3);
        a4 = fmaf(__uint_as_float(__builtin_amdgcn_readlane((unsigned)ev.y, j + 4)), g4, a4);
        a5 = fmaf(__uint_as_float(__builtin_amdgcn_readlane((unsigned)ev.y, j + 5)), g5, a5);
        a6 = fmaf(__uint_as_float(__builtin_amdgcn_readlane((unsigned)ev.y, j + 6)), g6, a6);
        a7 = fmaf(__uint_as_float(__builtin_amdgcn_readlane((unsigned)ev.y, j + 7)), g7, a7);
      }
    }
    float acc = ((a0 + a1) + (a2 + a3)) + ((a4 + a5) + (a6 + a7));
    if (lane < 47) out[(size_t)n * 47 + lane] = acc;
  }
}

extern "C" void kernel_launch(void* const* d_in, const int* in_sizes, int n_in,
                              void* d_out, int out_size, void* d_ws, size_t ws_size,
                              hipStream_t stream) {
  const float* x = (const float*)d_in[0];
  const float* adj_vals = (const float*)d_in[1];
  const int* adj_row = (const int*)d_in[2];
  const int* adj_col = (const int*)d_in[3];
  const float* gamma = (const float*)d_in[4];
  const float* beta = (const float*)d_in[5];
  const float* W1 = (const float*)d_in[6];
  const float* b1 = (const float*)d_in[7];
  const float* W2 = (const float*)d_in[8];
  const float* b2 = (const float*)d_in[9];
  const float* W3 = (const float*)d_in[10];
  const float* b3 = (const float*)d_in[11];
  float* out = (float*)d_out;

  char* ws = (char*)d_ws;
  size_t off = 0;
  auto alloc = [&](size_t bytes) -> void* {
    void* p = ws + off;
    off += (bytes + 255) & ~(size_t)255;
    return p;
  };
  float* bufA = (float*)alloc(sizeof(float) * (size_t)N_NODES_C * 64);
  float* bufB = (float*)alloc(sizeof(float) * (size_t)N_NODES_C * 64);
  int* counts = (int*)alloc(sizeof(int) * N_NODES_C);
  int* cursor = (int*)alloc(sizeof(int) * N_NODES_C);
  int* rowstart = (int*)alloc(sizeof(int) * N_NODES_C);
  int* bsums = (int*)alloc(sizeof(int) * 256);
  int2* edges_s = (int2*)alloc(sizeof(int2) * N_EDGES_C);

  hipMemsetAsync(counts, 0, sizeof(int) * N_NODES_C, stream);

  hist_kernel<<<2048, 256, 0, stream>>>(adj_row, counts);
  int nb = (N_NODES_C + 1023) / 1024;  // 98
  scan1_kernel<<<nb, 256, 0, stream>>>(counts, rowstart, bsums);
  scan2_kernel<<<1, 128, 0, stream>>>(bsums, nb);
  scan3_kernel<<<nb, 256, 0, stream>>>(rowstart, cursor, bsums);
  scatter_kernel<<<2048, 256, 0, stream>>>(adj_row, adj_col, adj_vals, cursor, edges_s);

  // h1 = LN(clamp(x)) @ W1 + b1
  ln_gemm1_kernel<<<1024, 256, 0, stream>>>(x, gamma, beta, W1, b1, bufA);
  // h2 = ELU(spmm(h1)) @ W2 + b2   (gather pitch 64 -> store pitch 64)
  spmm_elu_gemm_kernel<64, 64><<<2048, 256, 0, stream>>>(rowstart, counts, edges_s, bufA,
                                                         W2, b2, bufB);
  // h3 = ELU(spmm(h2)) @ W3 + b3   (gather pitch 64 -> store pitch 48, 47 valid)
  spmm_elu_gemm_kernel<47, 48><<<2048, 256, 0, stream>>>(rowstart, counts, edges_s, bufB,
                                                         W3, b3, bufA);
  // out = spmm(h3)
  spmm_final_kernel<<<2048, 256, 0, stream>>>(rowstart, counts, edges_s, bufA, out);
}

// Round 8
// 472.867 us; speedup vs baseline: 1.4657x; 1.0363x over previous
//
#include <hip/hip_runtime.h>
#include <cstdint>
#include <cstddef>

#define N_NODES_C 100000
#define N_EDGES_C 1600000
#define LN_EPS_C 1e-5f
#define CLAMP_C 1.8f

__device__ __forceinline__ float readlane_f(float v, int l) {
  return __uint_as_float(__builtin_amdgcn_readlane(__float_as_uint(v), l));
}

__device__ __forceinline__ float wave_sum(float v) {
#pragma unroll
  for (int off = 32; off > 0; off >>= 1) v += __shfl_xor(v, off, 64);
  return v;
}

// ---------------- CSR build ----------------
__global__ void hist_kernel(const int* __restrict__ row, int* __restrict__ counts) {
  int stride = gridDim.x * blockDim.x;
  for (int e = blockIdx.x * blockDim.x + threadIdx.x; e < N_EDGES_C; e += stride)
    atomicAdd(&counts[row[e]], 1);
}

__global__ void scan1_kernel(const int* __restrict__ counts, int* __restrict__ rowstart,
                             int* __restrict__ bsums) {
  __shared__ int lds[256];
  int t = threadIdx.x;
  int base = blockIdx.x * 1024 + t * 4;
  int c0 = (base + 0 < N_NODES_C) ? counts[base + 0] : 0;
  int c1 = (base + 1 < N_NODES_C) ? counts[base + 1] : 0;
  int c2 = (base + 2 < N_NODES_C) ? counts[base + 2] : 0;
  int c3 = (base + 3 < N_NODES_C) ? counts[base + 3] : 0;
  int s = c0 + c1 + c2 + c3;
  lds[t] = s;
  __syncthreads();
#pragma unroll
  for (int off = 1; off < 256; off <<= 1) {
    int v = (t >= off) ? lds[t - off] : 0;
    __syncthreads();
    lds[t] += v;
    __syncthreads();
  }
  int incl = lds[t];
  int excl = incl - s;
  if (t == 255) bsums[blockIdx.x] = incl;
  if (base + 0 < N_NODES_C) rowstart[base + 0] = excl;
  excl += c0;
  if (base + 1 < N_NODES_C) rowstart[base + 1] = excl;
  excl += c1;
  if (base + 2 < N_NODES_C) rowstart[base + 2] = excl;
  excl += c2;
  if (base + 3 < N_NODES_C) rowstart[base + 3] = excl;
}

__global__ void scan2_kernel(int* __restrict__ bsums, int nb) {
  __shared__ int lds[128];
  int t = threadIdx.x;
  int v = (t < nb) ? bsums[t] : 0;
  lds[t] = v;
  __syncthreads();
#pragma unroll
  for (int off = 1; off < 128; off <<= 1) {
    int u = (t >= off) ? lds[t - off] : 0;
    __syncthreads();
    lds[t] += u;
    __syncthreads();
  }
  if (t < nb) bsums[t] = lds[t] - v;
}

// writes final rowstart AND an identical cursor copy for the scatter pass
__global__ void scan3_kernel(int* __restrict__ rowstart, int* __restrict__ cursor,
                             const int* __restrict__ bsums) {
  int add = bsums[blockIdx.x];
  int base = blockIdx.x * 1024 + threadIdx.x * 4;
#pragma unroll
  for (int i = 0; i < 4; ++i)
    if (base + i < N_NODES_C) {
      int v = rowstart[base + i] + add;
      rowstart[base + i] = v;
      cursor[base + i] = v;
    }
}

// packed (col,val) scatter with 8-way MLP: load 8 edges, issue 8 independent
// atomics (all in flight), then 8 stores.
__global__ __launch_bounds__(256) void scatter_kernel(
    const int* __restrict__ row, const int* __restrict__ col,
    const float* __restrict__ vals, int* __restrict__ cursor,
    int2* __restrict__ edges_s) {
  int tid = blockIdx.x * blockDim.x + threadIdx.x;
  int nt = gridDim.x * blockDim.x;
  int r[8], c[8], p[8];
  float v[8];
#pragma unroll
  for (int k = 0; k < 8; ++k) {
    int e = tid + k * nt;
    bool in = e < N_EDGES_C;
    r[k] = in ? row[e] : 0;
    c[k] = in ? col[e] : 0;
    v[k] = in ? vals[e] : 0.f;
  }
#pragma unroll
  for (int k = 0; k < 8; ++k) {
    int e = tid + k * nt;
    if (e < N_EDGES_C) p[k] = atomicAdd(&cursor[r[k]], 1);
  }
#pragma unroll
  for (int k = 0; k < 8; ++k) {
    int e = tid + k * nt;
    if (e < N_EDGES_C) edges_s[p[k]] = make_int2(c[k], __float_as_int(v[k]));
  }
}

// ---------------- clamp + LayerNorm + GEMM1 (100 -> 64) ----------------
__global__ __launch_bounds__(256) void ln_gemm1_kernel(
    const float* __restrict__ x, const float* __restrict__ gamma, const float* __restrict__ beta,
    const float* __restrict__ W1, const float* __restrict__ b1, float* __restrict__ y) {
  int lane = threadIdx.x & 63;
  int wid = blockIdx.x * (blockDim.x >> 6) + (threadIdx.x >> 6);
  int nw = gridDim.x * (blockDim.x >> 6);
  float w[100];
#pragma unroll
  for (int k = 0; k < 100; ++k) w[k] = W1[k * 64 + lane];
  float bias = b1[lane];
  float g0 = gamma[lane];
  float be0 = beta[lane];
  float g1 = (lane < 36) ? gamma[64 + lane] : 0.f;
  float be1 = (lane < 36) ? beta[64 + lane] : 0.f;
  for (int n = wid; n < N_NODES_C; n += nw) {
    const float* xr = x + (size_t)n * 100;
    float x0 = xr[lane];
    float x1 = (lane < 36) ? xr[64 + lane] : 0.f;
    x0 = fminf(fmaxf(x0, -CLAMP_C), CLAMP_C);
    x1 = fminf(fmaxf(x1, -CLAMP_C), CLAMP_C);
    float mu = wave_sum(x0 + x1) * 0.01f;
    float d0 = x0 - mu;
    float d1 = (lane < 36) ? (x1 - mu) : 0.f;
    float var = wave_sum(d0 * d0 + d1 * d1) * 0.01f;
    float inv = rsqrtf(var + LN_EPS_C);
    float xn0 = d0 * inv * g0 + be0;
    float xn1 = d1 * inv * g1 + be1;
    float acc = bias;
#pragma unroll
    for (int k = 0; k < 64; ++k) acc = fmaf(readlane_f(xn0, k), w[k], acc);
#pragma unroll
    for (int k = 0; k < 36; ++k) acc = fmaf(readlane_f(xn1, k), w[64 + k], acc);
    y[(size_t)n * 64 + lane] = acc;
  }
}

// ---------------- SpMM core with 8-way gather ILP ----------------
template <int DOUT, int OPITCH>
__global__ __launch_bounds__(256) void spmm_elu_gemm_kernel(
    const int* __restrict__ rowstart, const int* __restrict__ counts,
    const int2* __restrict__ edges_s, const float* __restrict__ y,
    const float* __restrict__ W, const float* __restrict__ b, float* __restrict__ out) {
  int lane = threadIdx.x & 63;
  int wid = blockIdx.x * (blockDim.x >> 6) + (threadIdx.x >> 6);
  int nw = gridDim.x * (blockDim.x >> 6);
  float w[64];
#pragma unroll
  for (int k = 0; k < 64; ++k) w[k] = (lane < DOUT) ? W[k * DOUT + lane] : 0.f;
  float bias = (lane < DOUT) ? b[lane] : 0.f;
  for (int n = wid; n < N_NODES_C; n += nw) {
    int start = rowstart[n];
    int cnt = counts[n];
    float a0 = 0.f, a1 = 0.f, a2 = 0.f, a3 = 0.f, a4 = 0.f, a5 = 0.f, a6 = 0.f, a7 = 0.f;
    for (int base = 0; base < cnt; base += 64) {
      int m = cnt - base;
      if (m > 64) m = 64;
      int2 ev = make_int2(0, 0);
      if (lane < m) ev = edges_s[start + base + lane];
      int mr = (m + 7) & ~7;
      for (int j = 0; j < mr; j += 8) {
        float g0 = y[(size_t)__builtin_amdgcn_readlane(ev.x, j + 0) * 64 + lane];
        float g1 = y[(size_t)__builtin_amdgcn_readlane(ev.x, j + 1) * 64 + lane];
        float g2 = y[(size_t)__builtin_amdgcn_readlane(ev.x, j + 2) * 64 + lane];
        float g3 = y[(size_t)__builtin_amdgcn_readlane(ev.x, j + 3) * 64 + lane];
        float g4 = y[(size_t)__builtin_amdgcn_readlane(ev.x, j + 4) * 64 + lane];
        float g5 = y[(size_t)__builtin_amdgcn_readlane(ev.x, j + 5) * 64 + lane];
        float g6 = y[(size_t)__builtin_amdgcn_readlane(ev.x, j + 6) * 64 + lane];
        float g7 = y[(size_t)__builtin_amdgcn_readlane(ev.x, j + 7) * 64 + lane];
        a0 = fmaf(__uint_as_float(__builtin_amdgcn_readlane((unsigned)ev.y, j + 0)), g0, a0);
        a1 = fmaf(__uint_as_float(__builtin_amdgcn_readlane((unsigned)ev.y, j + 1)), g1, a1);
        a2 = fmaf(__uint_as_float(__builtin_amdgcn_readlane((unsigned)ev.y, j + 2)), g2, a2);
        a3 = fmaf(__uint_as_float(__builtin_amdgcn_readlane((unsigned)ev.y, j + 3)), g3, a3);
        a4 = fmaf(__uint_as_float(__builtin_amdgcn_readlane((unsigned)ev.y, j + 4)), g4, a4);
        a5 = fmaf(__uint_as_float(__builtin_amdgcn_readlane((unsigned)ev.y, j + 5)), g5, a5);
        a6 = fmaf(__uint_as_float(__builtin_amdgcn_readlane((unsigned)ev.y, j + 6)), g6, a6);
        a7 = fmaf(__uint_as_float(__builtin_amdgcn_readlane((unsigned)ev.y, j + 7)), g7, a7);
      }
    }
    float acc = ((a0 + a1) + (a2 + a3)) + ((a4 + a5) + (a6 + a7));
    // ELU
    float xe = (acc > 0.f) ? acc : expm1f(acc);
    // GEMM: out[n][lane] = bias + sum_k xe_k * W[k][lane]
    float o = bias;
#pragma unroll
    for (int k = 0; k < 64; ++k) o = fmaf(readlane_f(xe, k), w[k], o);
    if (lane < DOUT) out[(size_t)n * OPITCH + lane] = o;
  }
}

// ---------------- final SpMM (gather pitch 48, 47 valid) -> d_out ----------------
__global__ __launch_bounds__(256) void spmm_final_kernel(
    const int* __restrict__ rowstart, const int* __restrict__ counts,
    const int2* __restrict__ edges_s, const float* __restrict__ y,
    float* __restrict__ out) {
  int lane = threadIdx.x & 63;
  int wid = blockIdx.x * (blockDim.x >> 6) + (threadIdx.x >> 6);
  int nw = gridDim.x * (blockDim.x >> 6);
  int lmask = (lane < 47) ? lane : 46;  // keep OOB lanes inside the row (values unused)
  for (int n = wid; n < N_NODES_C; n += nw) {
    int start = rowstart[n];
    int cnt = counts[n];
    float a0 = 0.f, a1 = 0.f, a2 = 0.f, a3 = 0.f, a4 = 0.f, a5 = 0.f, a6 = 0.f, a7 = 0.f;
    for (int base = 0; base < cnt; base += 64) {
      int m = cnt - base;
      if (m > 64) m = 64;
      int2 ev = make_int2(0, 0);
      if (lane < m) ev = edges_s[start + base + lane];
      int mr = (m + 7) & ~7;
      for (int j = 0; j < mr; j += 8) {
        float g0 = y[(size_t)__builtin_amdgcn_readlane(ev.x, j + 0) * 48 + lmask];
        float g1 = y[(size_t)__builtin_amdgcn_readlane(ev.x, j + 1) * 48 + lmask];
        float g2 = y[(size_t)__builtin_amdgcn_readlane(ev.x, j + 2) * 48 + lmask];
        float g3 = y[(size_t)__builtin_amdgcn_readlane(ev.x, j + 3) * 48 + lmask];
        float g4 = y[(size_t)__builtin_amdgcn_readlane(ev.x, j + 4) * 48 + lmask];
        float g5 = y[(size_t)__builtin_amdgcn_readlane(ev.x, j + 5) * 48 + lmask];
        float g6 = y[(size_t)__builtin_amdgcn_readlane(ev.x, j + 6) * 48 + lmask];
        float g7 = y[(size_t)__builtin_amdgcn_readlane(ev.x, j + 7) * 48 + lmask];
        a0 = fmaf(__uint_as_float(__builtin_amdgcn_readlane((unsigned)ev.y, j + 0)), g0, a0);
        a1 = fmaf(__uint_as_float(__builtin_amdgcn_readlane((unsigned)ev.y, j + 1)), g1, a1);
        a2 = fmaf(__uint_as_float(__builtin_amdgcn_readlane((unsigned)ev.y, j + 2)), g2, a2);
        a3 = fmaf(__uint_as_float(__builtin_amdgcn_readlane((unsigned)ev.y, j + 3)), g3, a3);
        a4 = fmaf(__uint_as_float(__builtin_amdgcn_readlane((unsigned)ev.y, j + 4)), g4, a4);
        a5 = fmaf(__uint_as_float(__builtin_amdgcn_readlane((unsigned)ev.y, j + 5)), g5, a5);
        a6 = fmaf(__uint_as_float(__builtin_amdgcn_readlane((unsigned)ev.y, j + 6)), g6, a6);
        a7 = fmaf(__uint_as_float(__builtin_amdgcn_readlane((unsigned)ev.y, j + 7)), g7, a7);
      }
    }
    float acc = ((a0 + a1) + (a2 + a3)) + ((a4 + a5) + (a6 + a7));
    if (lane < 47) out[(size_t)n * 47 + lane] = acc;
  }
}

extern "C" void kernel_launch(void* const* d_in, const int* in_sizes, int n_in,
                              void* d_out, int out_size, void* d_ws, size_t ws_size,
                              hipStream_t stream) {
  const float* x = (const float*)d_in[0];
  const float* adj_vals = (const float*)d_in[1];
  const int* adj_row = (const int*)d_in[2];
  const int* adj_col = (const int*)d_in[3];
  const float* gamma = (const float*)d_in[4];
  const float* beta = (const float*)d_in[5];
  const float* W1 = (const float*)d_in[6];
  const float* b1 = (const float*)d_in[7];
  const float* W2 = (const float*)d_in[8];
  const float* b2 = (const float*)d_in[9];
  const float* W3 = (const float*)d_in[10];
  const float* b3 = (const float*)d_in[11];
  float* out = (float*)d_out;

  char* ws = (char*)d_ws;
  size_t off = 0;
  auto alloc = [&](size_t bytes) -> void* {
    void* p = ws + off;
    off += (bytes + 255) & ~(size_t)255;
    return p;
  };
  float* bufA = (float*)alloc(sizeof(float) * (size_t)N_NODES_C * 64);
  float* bufB = (float*)alloc(sizeof(float) * (size_t)N_NODES_C * 64);
  int* counts = (int*)alloc(sizeof(int) * N_NODES_C);
  int* cursor = (int*)alloc(sizeof(int) * N_NODES_C);
  int* rowstart = (int*)alloc(sizeof(int) * N_NODES_C);
  int* bsums = (int*)alloc(sizeof(int) * 256);
  int2* edges_s = (int2*)alloc(sizeof(int2) * N_EDGES_C);

  hipMemsetAsync(counts, 0, sizeof(int) * N_NODES_C, stream);

  hist_kernel<<<2048, 256, 0, stream>>>(adj_row, counts);
  int nb = (N_NODES_C + 1023) / 1024;  // 98
  scan1_kernel<<<nb, 256, 0, stream>>>(counts, rowstart, bsums);
  scan2_kernel<<<1, 128, 0, stream>>>(bsums, nb);
  scan3_kernel<<<nb, 256, 0, stream>>>(rowstart, cursor, bsums);
  // 1024 blocks * 256 threads * 8 edges/thread = 2.097M slots >= 1.6M edges
  scatter_kernel<<<1024, 256, 0, stream>>>(adj_row, adj_col, adj_vals, cursor, edges_s);

  // h1 = LN(clamp(x)) @ W1 + b1
  ln_gemm1_kernel<<<1024, 256, 0, stream>>>(x, gamma, beta, W1, b1, bufA);
  // h2 = ELU(spmm(h1)) @ W2 + b2   (gather pitch 64 -> store pitch 64)
  spmm_elu_gemm_kernel<64, 64><<<2048, 256, 0, stream>>>(rowstart, counts, edges_s, bufA,
                                                         W2, b2, bufB);
  // h3 = ELU(spmm(h2)) @ W3 + b3   (gather pitch 64 -> store pitch 48, 47 valid)
  spmm_elu_gemm_kernel<47, 48><<<2048, 256, 0, stream>>>(rowstart, counts, edges_s, bufB,
                                                         W3, b3, bufA);
  // out = spmm(h3)
  spmm_final_kernel<<<2048, 256, 0, stream>>>(rowstart, counts, edges_s, bufA, out);
}

// Round 9
// 450.357 us; speedup vs baseline: 1.5390x; 1.0500x over previous
//
#include <hip/hip_runtime.h>
#include <cstdint>
#include <cstddef>

#define N_NODES_C 100000
#define N_EDGES_C 1600000
#define LN_EPS_C 1e-5f
#define CLAMP_C 1.8f
#define SC_BLOCKS 1024
#define LN_BLOCKS 1024

typedef unsigned short ushort_t;

__device__ __forceinline__ float readlane_f(float v, int l) {
  return __uint_as_float(__builtin_amdgcn_readlane(__float_as_uint(v), l));
}

__device__ __forceinline__ float wave_sum(float v) {
#pragma unroll
  for (int off = 32; off > 0; off >>= 1) v += __shfl_xor(v, off, 64);
  return v;
}

// bf16 pack (round-to-nearest-even) / unpack
__device__ __forceinline__ ushort_t f2bf(float f) {
  unsigned u = __float_as_uint(f);
  unsigned r = (u + 0x7fffu + ((u >> 16) & 1u)) >> 16;
  return (ushort_t)r;
}
__device__ __forceinline__ float bf2f(ushort_t u) {
  return __uint_as_float((unsigned)u << 16);
}

// ---------------- CSR build ----------------
__global__ void hist_kernel(const int* __restrict__ row, int* __restrict__ counts) {
  int stride = gridDim.x * blockDim.x;
  for (int e = blockIdx.x * blockDim.x + threadIdx.x; e < N_EDGES_C; e += stride)
    atomicAdd(&counts[row[e]], 1);
}

__global__ void scan1_kernel(const int* __restrict__ counts, int* __restrict__ rowstart,
                             int* __restrict__ bsums) {
  __shared__ int lds[256];
  int t = threadIdx.x;
  int base = blockIdx.x * 1024 + t * 4;
  int c0 = (base + 0 < N_NODES_C) ? counts[base + 0] : 0;
  int c1 = (base + 1 < N_NODES_C) ? counts[base + 1] : 0;
  int c2 = (base + 2 < N_NODES_C) ? counts[base + 2] : 0;
  int c3 = (base + 3 < N_NODES_C) ? counts[base + 3] : 0;
  int s = c0 + c1 + c2 + c3;
  lds[t] = s;
  __syncthreads();
#pragma unroll
  for (int off = 1; off < 256; off <<= 1) {
    int v = (t >= off) ? lds[t - off] : 0;
    __syncthreads();
    lds[t] += v;
    __syncthreads();
  }
  int incl = lds[t];
  int excl = incl - s;
  if (t == 255) bsums[blockIdx.x] = incl;
  if (base + 0 < N_NODES_C) rowstart[base + 0] = excl;
  excl += c0;
  if (base + 1 < N_NODES_C) rowstart[base + 1] = excl;
  excl += c1;
  if (base + 2 < N_NODES_C) rowstart[base + 2] = excl;
  excl += c2;
  if (base + 3 < N_NODES_C) rowstart[base + 3] = excl;
}

__global__ void scan2_kernel(int* __restrict__ bsums, int nb) {
  __shared__ int lds[128];
  int t = threadIdx.x;
  int v = (t < nb) ? bsums[t] : 0;
  lds[t] = v;
  __syncthreads();
#pragma unroll
  for (int off = 1; off < 128; off <<= 1) {
    int u = (t >= off) ? lds[t - off] : 0;
    __syncthreads();
    lds[t] += u;
    __syncthreads();
  }
  if (t < nb) bsums[t] = lds[t] - v;
}

__global__ void scan3_kernel(int* __restrict__ rowstart, int* __restrict__ cursor,
                             const int* __restrict__ bsums) {
  int add = bsums[blockIdx.x];
  int base = blockIdx.x * 1024 + threadIdx.x * 4;
#pragma unroll
  for (int i = 0; i < 4; ++i)
    if (base + i < N_NODES_C) {
      int v = rowstart[base + i] + add;
      rowstart[base + i] = v;
      cursor[base + i] = v;
    }
}

// ---------------- fused scatter (blocks [0,SC_BLOCKS)) + LN/GEMM1 (rest) ----------
// scatter: fabric-bound (VALU ~1%); ln: VALU-bound -> co-resident, ln hides
// under scatter.
__global__ __launch_bounds__(256) void scatter_ln_kernel(
    const int* __restrict__ row, const int* __restrict__ col,
    const float* __restrict__ vals, int* __restrict__ cursor,
    int2* __restrict__ edges_s,
    const float* __restrict__ x, const float* __restrict__ gamma,
    const float* __restrict__ beta, const float* __restrict__ W1,
    const float* __restrict__ b1, ushort_t* __restrict__ y) {
  if (blockIdx.x < SC_BLOCKS) {
    int tid = blockIdx.x * 256 + threadIdx.x;
    const int nt = SC_BLOCKS * 256;
    int r[8], c[8], p[8];
    float v[8];
#pragma unroll
    for (int k = 0; k < 8; ++k) {
      int e = tid + k * nt;
      bool in = e < N_EDGES_C;
      r[k] = in ? row[e] : 0;
      c[k] = in ? col[e] : 0;
      v[k] = in ? vals[e] : 0.f;
    }
#pragma unroll
    for (int k = 0; k < 8; ++k) {
      int e = tid + k * nt;
      if (e < N_EDGES_C) p[k] = atomicAdd(&cursor[r[k]], 1);
    }
#pragma unroll
    for (int k = 0; k < 8; ++k) {
      int e = tid + k * nt;
      if (e < N_EDGES_C) edges_s[p[k]] = make_int2(c[k], __float_as_int(v[k]));
    }
  } else {
    int lane = threadIdx.x & 63;
    int wid = (blockIdx.x - SC_BLOCKS) * 4 + (threadIdx.x >> 6);
    const int nw = LN_BLOCKS * 4;
    float w[100];
#pragma unroll
    for (int k = 0; k < 100; ++k) w[k] = W1[k * 64 + lane];
    float bias = b1[lane];
    float g0 = gamma[lane];
    float be0 = beta[lane];
    float g1 = (lane < 36) ? gamma[64 + lane] : 0.f;
    float be1 = (lane < 36) ? beta[64 + lane] : 0.f;
    for (int n = wid; n < N_NODES_C; n += nw) {
      const float* xr = x + (size_t)n * 100;
      float x0 = xr[lane];
      float x1 = (lane < 36) ? xr[64 + lane] : 0.f;
      x0 = fminf(fmaxf(x0, -CLAMP_C), CLAMP_C);
      x1 = fminf(fmaxf(x1, -CLAMP_C), CLAMP_C);
      float mu = wave_sum(x0 + x1) * 0.01f;
      float d0 = x0 - mu;
      float d1 = (lane < 36) ? (x1 - mu) : 0.f;
      float var = wave_sum(d0 * d0 + d1 * d1) * 0.01f;
      float inv = rsqrtf(var + LN_EPS_C);
      float xn0 = d0 * inv * g0 + be0;
      float xn1 = d1 * inv * g1 + be1;
      float acc = bias;
#pragma unroll
      for (int k = 0; k < 64; ++k) acc = fmaf(readlane_f(xn0, k), w[k], acc);
#pragma unroll
      for (int k = 0; k < 36; ++k) acc = fmaf(readlane_f(xn1, k), w[64 + k], acc);
      y[(size_t)n * 64 + lane] = f2bf(acc);
    }
  }
}

// ---------------- SpMM (bf16 gather) + ELU + GEMM(64->DOUT), bf16 out --------
template <int DOUT>
__global__ __launch_bounds__(256) void spmm_elu_gemm_kernel(
    const int* __restrict__ rowstart, const int* __restrict__ counts,
    const int2* __restrict__ edges_s, const ushort_t* __restrict__ yb,
    const float* __restrict__ W, const float* __restrict__ b,
    ushort_t* __restrict__ out) {
  int lane = threadIdx.x & 63;
  int wid = blockIdx.x * (blockDim.x >> 6) + (threadIdx.x >> 6);
  int nw = gridDim.x * (blockDim.x >> 6);
  float w[64];
#pragma unroll
  for (int k = 0; k < 64; ++k) w[k] = (lane < DOUT) ? W[k * DOUT + lane] : 0.f;
  float bias = (lane < DOUT) ? b[lane] : 0.f;
  for (int n = wid; n < N_NODES_C; n += nw) {
    int start = rowstart[n];
    int cnt = counts[n];
    float a0 = 0.f, a1 = 0.f, a2 = 0.f, a3 = 0.f, a4 = 0.f, a5 = 0.f, a6 = 0.f, a7 = 0.f;
    for (int base = 0; base < cnt; base += 64) {
      int m = cnt - base;
      if (m > 64) m = 64;
      int2 ev = make_int2(0, 0);
      if (lane < m) ev = edges_s[start + base + lane];
      int mr = (m + 7) & ~7;
      for (int j = 0; j < mr; j += 8) {
        float g0 = bf2f(yb[(size_t)__builtin_amdgcn_readlane(ev.x, j + 0) * 64 + lane]);
        float g1 = bf2f(yb[(size_t)__builtin_amdgcn_readlane(ev.x, j + 1) * 64 + lane]);
        float g2 = bf2f(yb[(size_t)__builtin_amdgcn_readlane(ev.x, j + 2) * 64 + lane]);
        float g3 = bf2f(yb[(size_t)__builtin_amdgcn_readlane(ev.x, j + 3) * 64 + lane]);
        float g4 = bf2f(yb[(size_t)__builtin_amdgcn_readlane(ev.x, j + 4) * 64 + lane]);
        float g5 = bf2f(yb[(size_t)__builtin_amdgcn_readlane(ev.x, j + 5) * 64 + lane]);
        float g6 = bf2f(yb[(size_t)__builtin_amdgcn_readlane(ev.x, j + 6) * 64 + lane]);
        float g7 = bf2f(yb[(size_t)__builtin_amdgcn_readlane(ev.x, j + 7) * 64 + lane]);
        a0 = fmaf(__uint_as_float(__builtin_amdgcn_readlane((unsigned)ev.y, j + 0)), g0, a0);
        a1 = fmaf(__uint_as_float(__builtin_amdgcn_readlane((unsigned)ev.y, j + 1)), g1, a1);
        a2 = fmaf(__uint_as_float(__builtin_amdgcn_readlane((unsigned)ev.y, j + 2)), g2, a2);
        a3 = fmaf(__uint_as_float(__builtin_amdgcn_readlane((unsigned)ev.y, j + 3)), g3, a3);
        a4 = fmaf(__uint_as_float(__builtin_amdgcn_readlane((unsigned)ev.y, j + 4)), g4, a4);
        a5 = fmaf(__uint_as_float(__builtin_amdgcn_readlane((unsigned)ev.y, j + 5)), g5, a5);
        a6 = fmaf(__uint_as_float(__builtin_amdgcn_readlane((unsigned)ev.y, j + 6)), g6, a6);
        a7 = fmaf(__uint_as_float(__builtin_amdgcn_readlane((unsigned)ev.y, j + 7)), g7, a7);
      }
    }
    float acc = ((a0 + a1) + (a2 + a3)) + ((a4 + a5) + (a6 + a7));
    // ELU
    float xe = (acc > 0.f) ? acc : expm1f(acc);
    // GEMM: out[n][lane] = bias + sum_k xe_k * W[k][lane]
    float o = bias;
#pragma unroll
    for (int k = 0; k < 64; ++k) o = fmaf(readlane_f(xe, k), w[k], o);
    if (lane < DOUT) out[(size_t)n * 64 + lane] = f2bf(o);
  }
}

// ---------------- final SpMM (bf16 gather pitch 64, 47 valid) -> fp32 out ----
__global__ __launch_bounds__(256) void spmm_final_kernel(
    const int* __restrict__ rowstart, const int* __restrict__ counts,
    const int2* __restrict__ edges_s, const ushort_t* __restrict__ yb,
    float* __restrict__ out) {
  int lane = threadIdx.x & 63;
  int wid = blockIdx.x * (blockDim.x >> 6) + (threadIdx.x >> 6);
  int nw = gridDim.x * (blockDim.x >> 6);
  int lmask = (lane < 47) ? lane : 46;  // OOB lanes stay inside the row; unused
  for (int n = wid; n < N_NODES_C; n += nw) {
    int start = rowstart[n];
    int cnt = counts[n];
    float a0 = 0.f, a1 = 0.f, a2 = 0.f, a3 = 0.f, a4 = 0.f, a5 = 0.f, a6 = 0.f, a7 = 0.f;
    for (int base = 0; base < cnt; base += 64) {
      int m = cnt - base;
      if (m > 64) m = 64;
      int2 ev = make_int2(0, 0);
      if (lane < m) ev = edges_s[start + base + lane];
      int mr = (m + 7) & ~7;
      for (int j = 0; j < mr; j += 8) {
        float g0 = bf2f(yb[(size_t)__builtin_amdgcn_readlane(ev.x, j + 0) * 64 + lmask]);
        float g1 = bf2f(yb[(size_t)__builtin_amdgcn_readlane(ev.x, j + 1) * 64 + lmask]);
        float g2 = bf2f(yb[(size_t)__builtin_amdgcn_readlane(ev.x, j + 2) * 64 + lmask]);
        float g3 = bf2f(yb[(size_t)__builtin_amdgcn_readlane(ev.x, j + 3) * 64 + lmask]);
        float g4 = bf2f(yb[(size_t)__builtin_amdgcn_readlane(ev.x, j + 4) * 64 + lmask]);
        float g5 = bf2f(yb[(size_t)__builtin_amdgcn_readlane(ev.x, j + 5) * 64 + lmask]);
        float g6 = bf2f(yb[(size_t)__builtin_amdgcn_readlane(ev.x, j + 6) * 64 + lmask]);
        float g7 = bf2f(yb[(size_t)__builtin_amdgcn_readlane(ev.x, j + 7) * 64 + lmask]);
        a0 = fmaf(__uint_as_float(__builtin_amdgcn_readlane((unsigned)ev.y, j + 0)), g0, a0);
        a1 = fmaf(__uint_as_float(__builtin_amdgcn_readlane((unsigned)ev.y, j + 1)), g1, a1);
        a2 = fmaf(__uint_as_float(__builtin_amdgcn_readlane((unsigned)ev.y, j + 2)), g2, a2);
        a3 = fmaf(__uint_as_float(__builtin_amdgcn_readlane((unsigned)ev.y, j + 3)), g3, a3);
        a4 = fmaf(__uint_as_float(__builtin_amdgcn_readlane((unsigned)ev.y, j + 4)), g4, a4);
        a5 = fmaf(__uint_as_float(__builtin_amdgcn_readlane((unsigned)ev.y, j + 5)), g5, a5);
        a6 = fmaf(__uint_as_float(__builtin_amdgcn_readlane((unsigned)ev.y, j + 6)), g6, a6);
        a7 = fmaf(__uint_as_float(__builtin_amdgcn_readlane((unsigned)ev.y, j + 7)), g7, a7);
      }
    }
    float acc = ((a0 + a1) + (a2 + a3)) + ((a4 + a5) + (a6 + a7));
    if (lane < 47) out[(size_t)n * 47 + lane] = acc;
  }
}

extern "C" void kernel_launch(void* const* d_in, const int* in_sizes, int n_in,
                              void* d_out, int out_size, void* d_ws, size_t ws_size,
                              hipStream_t stream) {
  const float* x = (const float*)d_in[0];
  const float* adj_vals = (const float*)d_in[1];
  const int* adj_row = (const int*)d_in[2];
  const int* adj_col = (const int*)d_in[3];
  const float* gamma = (const float*)d_in[4];
  const float* beta = (const float*)d_in[5];
  const float* W1 = (const float*)d_in[6];
  const float* b1 = (const float*)d_in[7];
  const float* W2 = (const float*)d_in[8];
  const float* b2 = (const float*)d_in[9];
  const float* W3 = (const float*)d_in[10];
  const float* b3 = (const float*)d_in[11];
  float* out = (float*)d_out;

  char* ws = (char*)d_ws;
  size_t off = 0;
  auto alloc = [&](size_t bytes) -> void* {
    void* p = ws + off;
    off += (bytes + 255) & ~(size_t)255;
    return p;
  };
  ushort_t* bufA = (ushort_t*)alloc(sizeof(ushort_t) * (size_t)N_NODES_C * 64);
  ushort_t* bufB = (ushort_t*)alloc(sizeof(ushort_t) * (size_t)N_NODES_C * 64);
  int* counts = (int*)alloc(sizeof(int) * N_NODES_C);
  int* cursor = (int*)alloc(sizeof(int) * N_NODES_C);
  int* rowstart = (int*)alloc(sizeof(int) * N_NODES_C);
  int* bsums = (int*)alloc(sizeof(int) * 256);
  int2* edges_s = (int2*)alloc(sizeof(int2) * N_EDGES_C);

  hipMemsetAsync(counts, 0, sizeof(int) * N_NODES_C, stream);

  hist_kernel<<<2048, 256, 0, stream>>>(adj_row, counts);
  int nb = (N_NODES_C + 1023) / 1024;  // 98
  scan1_kernel<<<nb, 256, 0, stream>>>(counts, rowstart, bsums);
  scan2_kernel<<<1, 128, 0, stream>>>(bsums, nb);
  scan3_kernel<<<nb, 256, 0, stream>>>(rowstart, cursor, bsums);

  // fused: blocks [0,1024) scatter edges; blocks [1024,2048) LN+GEMM1 -> bf16
  scatter_ln_kernel<<<SC_BLOCKS + LN_BLOCKS, 256, 0, stream>>>(
      adj_row, adj_col, adj_vals, cursor, edges_s, x, gamma, beta, W1, b1, bufA);

  // h2 = ELU(spmm(h1)) @ W2 + b2   (bf16 in/out, pitch 64)
  spmm_elu_gemm_kernel<64><<<2048, 256, 0, stream>>>(rowstart, counts, edges_s, bufA,
                                                     W2, b2, bufB);
  // h3 = ELU(spmm(h2)) @ W3 + b3   (bf16 in/out, pitch 64, 47 valid)
  spmm_elu_gemm_kernel<47><<<2048, 256, 0, stream>>>(rowstart, counts, edges_s, bufB,
                                                     W3, b3, bufA);
  // out = spmm(h3)  (fp32 out)
  spmm_final_kernel<<<2048, 256, 0, stream>>>(rowstart, counts, edges_s, bufA, out);
}

// Round 10
// 403.420 us; speedup vs baseline: 1.7180x; 1.1163x over previous
//
#include <hip/hip_runtime.h>
#include <cstdint>
#include <cstddef>

#define N_NODES_C 100000
#define N_EDGES_C 1600000
#define LN_EPS_C 1e-5f
#define CLAMP_C 1.8f
#define SC_BLOCKS 1024
#define LN_BLOCKS 1024

typedef unsigned short ushort_t;

__device__ __forceinline__ float readlane_f(float v, int l) {
  return __uint_as_float(__builtin_amdgcn_readlane(__float_as_uint(v), l));
}

__device__ __forceinline__ float wave_sum(float v) {
#pragma unroll
  for (int off = 32; off > 0; off >>= 1) v += __shfl_xor(v, off, 64);
  return v;
}

// bf16 pack (round-to-nearest-even) / unpack
__device__ __forceinline__ ushort_t f2bf(float f) {
  unsigned u = __float_as_uint(f);
  unsigned r = (u + 0x7fffu + ((u >> 16) & 1u)) >> 16;
  return (ushort_t)r;
}
__device__ __forceinline__ float bf2f(ushort_t u) {
  return __uint_as_float((unsigned)u << 16);
}

// ---------------- CSR build ----------------
__global__ void hist_kernel(const int* __restrict__ row, int* __restrict__ counts) {
  int stride = gridDim.x * blockDim.x;
  for (int e = blockIdx.x * blockDim.x + threadIdx.x; e < N_EDGES_C; e += stride)
    atomicAdd(&counts[row[e]], 1);
}

__global__ void scan1_kernel(const int* __restrict__ counts, int* __restrict__ rowstart,
                             int* __restrict__ bsums) {
  __shared__ int lds[256];
  int t = threadIdx.x;
  int base = blockIdx.x * 1024 + t * 4;
  int c0 = (base + 0 < N_NODES_C) ? counts[base + 0] : 0;
  int c1 = (base + 1 < N_NODES_C) ? counts[base + 1] : 0;
  int c2 = (base + 2 < N_NODES_C) ? counts[base + 2] : 0;
  int c3 = (base + 3 < N_NODES_C) ? counts[base + 3] : 0;
  int s = c0 + c1 + c2 + c3;
  lds[t] = s;
  __syncthreads();
#pragma unroll
  for (int off = 1; off < 256; off <<= 1) {
    int v = (t >= off) ? lds[t - off] : 0;
    __syncthreads();
    lds[t] += v;
    __syncthreads();
  }
  int incl = lds[t];
  int excl = incl - s;
  if (t == 255) bsums[blockIdx.x] = incl;
  if (base + 0 < N_NODES_C) rowstart[base + 0] = excl;
  excl += c0;
  if (base + 1 < N_NODES_C) rowstart[base + 1] = excl;
  excl += c1;
  if (base + 2 < N_NODES_C) rowstart[base + 2] = excl;
  excl += c2;
  if (base + 3 < N_NODES_C) rowstart[base + 3] = excl;
}

__global__ void scan2_kernel(int* __restrict__ bsums, int nb) {
  __shared__ int lds[128];
  int t = threadIdx.x;
  int v = (t < nb) ? bsums[t] : 0;
  lds[t] = v;
  __syncthreads();
#pragma unroll
  for (int off = 1; off < 128; off <<= 1) {
    int u = (t >= off) ? lds[t - off] : 0;
    __syncthreads();
    lds[t] += u;
    __syncthreads();
  }
  if (t < nb) bsums[t] = lds[t] - v;
}

__global__ void scan3_kernel(int* __restrict__ rowstart, int* __restrict__ cursor,
                             const int* __restrict__ bsums) {
  int add = bsums[blockIdx.x];
  int base = blockIdx.x * 1024 + threadIdx.x * 4;
#pragma unroll
  for (int i = 0; i < 4; ++i)
    if (base + i < N_NODES_C) {
      int v = rowstart[base + i] + add;
      rowstart[base + i] = v;
      cursor[base + i] = v;
    }
}

// ---------------- fused scatter / LN+GEMM1, interleaved by blockIdx parity ----
// even blocks: fabric-bound edge scatter; odd blocks: VALU-bound LN+GEMM1.
// Parity interleave keeps both role sets co-resident from t=0 (range-split
// ran them serially: in-order block scheduling filled all CUs with scatter
// blocks first — round 9 post-mortem).
__global__ __launch_bounds__(256) void scatter_ln_kernel(
    const int* __restrict__ row, const int* __restrict__ col,
    const float* __restrict__ vals, int* __restrict__ cursor,
    int2* __restrict__ edges_s,
    const float* __restrict__ x, const float* __restrict__ gamma,
    const float* __restrict__ beta, const float* __restrict__ W1,
    const float* __restrict__ b1, ushort_t* __restrict__ y) {
  if ((blockIdx.x & 1) == 0) {
    int tid = (blockIdx.x >> 1) * 256 + threadIdx.x;
    const int nt = SC_BLOCKS * 256;
    int r[8], c[8], p[8];
    float v[8];
#pragma unroll
    for (int k = 0; k < 8; ++k) {
      int e = tid + k * nt;
      bool in = e < N_EDGES_C;
      r[k] = in ? row[e] : 0;
      c[k] = in ? col[e] : 0;
      v[k] = in ? vals[e] : 0.f;
    }
#pragma unroll
    for (int k = 0; k < 8; ++k) {
      int e = tid + k * nt;
      if (e < N_EDGES_C) p[k] = atomicAdd(&cursor[r[k]], 1);
    }
#pragma unroll
    for (int k = 0; k < 8; ++k) {
      int e = tid + k * nt;
      if (e < N_EDGES_C) edges_s[p[k]] = make_int2(c[k], __float_as_int(v[k]));
    }
  } else {
    int lane = threadIdx.x & 63;
    int wid = (blockIdx.x >> 1) * 4 + (threadIdx.x >> 6);
    const int nw = LN_BLOCKS * 4;
    float bias = b1[lane];
    float g0 = gamma[lane];
    float be0 = beta[lane];
    float g1 = (lane < 36) ? gamma[64 + lane] : 0.f;
    float be1 = (lane < 36) ? beta[64 + lane] : 0.f;
    for (int n = wid; n < N_NODES_C; n += nw) {
      const float* xr = x + (size_t)n * 100;
      float x0 = xr[lane];
      float x1 = (lane < 36) ? xr[64 + lane] : 0.f;
      x0 = fminf(fmaxf(x0, -CLAMP_C), CLAMP_C);
      x1 = fminf(fmaxf(x1, -CLAMP_C), CLAMP_C);
      float mu = wave_sum(x0 + x1) * 0.01f;
      float d0 = x0 - mu;
      float d1 = (lane < 36) ? (x1 - mu) : 0.f;
      float var = wave_sum(d0 * d0 + d1 * d1) * 0.01f;
      float inv = rsqrtf(var + LN_EPS_C);
      float xn0 = d0 * inv * g0 + be0;
      float xn1 = d1 * inv * g1 + be1;
      float acc = bias;
#pragma unroll
      for (int k = 0; k < 64; ++k) acc = fmaf(readlane_f(xn0, k), W1[k * 64 + lane], acc);
#pragma unroll
      for (int k = 0; k < 36; ++k) acc = fmaf(readlane_f(xn1, k), W1[(64 + k) * 64 + lane], acc);
      y[(size_t)n * 64 + lane] = f2bf(acc);
    }
  }
}

// ---------------- SpMM (bf16 gather, 16-way ILP) + ELU + GEMM(64->DOUT) ------
template <int DOUT>
__global__ __launch_bounds__(256) void spmm_elu_gemm_kernel(
    const int* __restrict__ rowstart, const int* __restrict__ counts,
    const int2* __restrict__ edges_s, const ushort_t* __restrict__ yb,
    const float* __restrict__ W, const float* __restrict__ b,
    ushort_t* __restrict__ out) {
  int lane = threadIdx.x & 63;
  int wid = blockIdx.x * (blockDim.x >> 6) + (threadIdx.x >> 6);
  int nw = gridDim.x * (blockDim.x >> 6);
  float w[64];
#pragma unroll
  for (int k = 0; k < 64; ++k) w[k] = (lane < DOUT) ? W[k * DOUT + lane] : 0.f;
  float bias = (lane < DOUT) ? b[lane] : 0.f;
  for (int n = wid; n < N_NODES_C; n += nw) {
    int start = rowstart[n];
    int cnt = counts[n];
    float a[8];
#pragma unroll
    for (int u = 0; u < 8; ++u) a[u] = 0.f;
    for (int base = 0; base < cnt; base += 64) {
      int m = cnt - base;
      if (m > 64) m = 64;
      int2 ev = make_int2(0, 0);
      if (lane < m) ev = edges_s[start + base + lane];
      int mr = (m + 15) & ~15;
      for (int j = 0; j < mr; j += 16) {
        float g[16];
#pragma unroll
        for (int u = 0; u < 16; ++u)
          g[u] = bf2f(yb[(size_t)__builtin_amdgcn_readlane(ev.x, j + u) * 64 + lane]);
#pragma unroll
        for (int u = 0; u < 16; ++u)
          a[u & 7] = fmaf(
              __uint_as_float(__builtin_amdgcn_readlane((unsigned)ev.y, j + u)), g[u],
              a[u & 7]);
      }
    }
    float acc = ((a[0] + a[1]) + (a[2] + a[3])) + ((a[4] + a[5]) + (a[6] + a[7]));
    // ELU
    float xe = (acc > 0.f) ? acc : expm1f(acc);
    // GEMM: out[n][lane] = bias + sum_k xe_k * W[k][lane]
    float o = bias;
#pragma unroll
    for (int k = 0; k < 64; ++k) o = fmaf(readlane_f(xe, k), w[k], o);
    if (lane < DOUT) out[(size_t)n * 64 + lane] = f2bf(o);
  }
}

// ---------------- final SpMM (bf16 gather, 16-way ILP, 47 valid) -> fp32 -----
__global__ __launch_bounds__(256) void spmm_final_kernel(
    const int* __restrict__ rowstart, const int* __restrict__ counts,
    const int2* __restrict__ edges_s, const ushort_t* __restrict__ yb,
    float* __restrict__ out) {
  int lane = threadIdx.x & 63;
  int wid = blockIdx.x * (blockDim.x >> 6) + (threadIdx.x >> 6);
  int nw = gridDim.x * (blockDim.x >> 6);
  int lmask = (lane < 47) ? lane : 46;  // OOB lanes stay inside the row; unused
  for (int n = wid; n < N_NODES_C; n += nw) {
    int start = rowstart[n];
    int cnt = counts[n];
    float a[8];
#pragma unroll
    for (int u = 0; u < 8; ++u) a[u] = 0.f;
    for (int base = 0; base < cnt; base += 64) {
      int m = cnt - base;
      if (m > 64) m = 64;
      int2 ev = make_int2(0, 0);
      if (lane < m) ev = edges_s[start + base + lane];
      int mr = (m + 15) & ~15;
      for (int j = 0; j < mr; j += 16) {
        float g[16];
#pragma unroll
        for (int u = 0; u < 16; ++u)
          g[u] = bf2f(yb[(size_t)__builtin_amdgcn_readlane(ev.x, j + u) * 64 + lmask]);
#pragma unroll
        for (int u = 0; u < 16; ++u)
          a[u & 7] = fmaf(
              __uint_as_float(__builtin_amdgcn_readlane((unsigned)ev.y, j + u)), g[u],
              a[u & 7]);
      }
    }
    float acc = ((a[0] + a[1]) + (a[2] + a[3])) + ((a[4] + a[5]) + (a[6] + a[7]));
    if (lane < 47) out[(size_t)n * 47 + lane] = acc;
  }
}

extern "C" void kernel_launch(void* const* d_in, const int* in_sizes, int n_in,
                              void* d_out, int out_size, void* d_ws, size_t ws_size,
                              hipStream_t stream) {
  const float* x = (const float*)d_in[0];
  const float* adj_vals = (const float*)d_in[1];
  const int* adj_row = (const int*)d_in[2];
  const int* adj_col = (const int*)d_in[3];
  const float* gamma = (const float*)d_in[4];
  const float* beta = (const float*)d_in[5];
  const float* W1 = (const float*)d_in[6];
  const float* b1 = (const float*)d_in[7];
  const float* W2 = (const float*)d_in[8];
  const float* b2 = (const float*)d_in[9];
  const float* W3 = (const float*)d_in[10];
  const float* b3 = (const float*)d_in[11];
  float* out = (float*)d_out;

  char* ws = (char*)d_ws;
  size_t off = 0;
  auto alloc = [&](size_t bytes) -> void* {
    void* p = ws + off;
    off += (bytes + 255) & ~(size_t)255;
    return p;
  };
  ushort_t* bufA = (ushort_t*)alloc(sizeof(ushort_t) * (size_t)N_NODES_C * 64);
  ushort_t* bufB = (ushort_t*)alloc(sizeof(ushort_t) * (size_t)N_NODES_C * 64);
  int* counts = (int*)alloc(sizeof(int) * N_NODES_C);
  int* cursor = (int*)alloc(sizeof(int) * N_NODES_C);
  int* rowstart = (int*)alloc(sizeof(int) * N_NODES_C);
  int* bsums = (int*)alloc(sizeof(int) * 256);
  int2* edges_s = (int2*)alloc(sizeof(int2) * N_EDGES_C);

  hipMemsetAsync(counts, 0, sizeof(int) * N_NODES_C, stream);

  hist_kernel<<<2048, 256, 0, stream>>>(adj_row, counts);
  int nb = (N_NODES_C + 1023) / 1024;  // 98
  scan1_kernel<<<nb, 256, 0, stream>>>(counts, rowstart, bsums);
  scan2_kernel<<<1, 128, 0, stream>>>(bsums, nb);
  scan3_kernel<<<nb, 256, 0, stream>>>(rowstart, cursor, bsums);

  // even blocks scatter edges, odd blocks LN+GEMM1 -> bf16 (co-resident overlap)
  scatter_ln_kernel<<<SC_BLOCKS + LN_BLOCKS, 256, 0, stream>>>(
      adj_row, adj_col, adj_vals, cursor, edges_s, x, gamma, beta, W1, b1, bufA);

  // h2 = ELU(spmm(h1)) @ W2 + b2   (bf16 in/out, pitch 64)
  spmm_elu_gemm_kernel<64><<<2048, 256, 0, stream>>>(rowstart, counts, edges_s, bufA,
                                                     W2, b2, bufB);
  // h3 = ELU(spmm(h2)) @ W3 + b3   (bf16 in/out, pitch 64, 47 valid)
  spmm_elu_gemm_kernel<47><<<2048, 256, 0, stream>>>(rowstart, counts, edges_s, bufB,
                                                     W3, b3, bufA);
  // out = spmm(h3)  (fp32 out)
  spmm_final_kernel<<<2048, 256, 0, stream>>>(rowstart, counts, edges_s, bufA, out);
}